// Round 4
// baseline (1142.328 us; speedup 1.0000x reference)
//
#include <hip/hip_runtime.h>
#include <stdint.h>

typedef short s16x8 __attribute__((ext_vector_type(8)));
typedef __bf16 bf16x8 __attribute__((ext_vector_type(8)));
typedef float f32x4 __attribute__((ext_vector_type(4)));

typedef const __attribute__((address_space(1))) void* gas_ptr;
typedef __attribute__((address_space(3))) void* las_ptr;

__device__ __forceinline__ unsigned short f2bf(float f) {
  unsigned u = __builtin_bit_cast(unsigned, f);
  u += 0x7FFFu + ((u >> 16) & 1u);   // round-to-nearest-even
  return (unsigned short)(u >> 16);
}
__device__ __forceinline__ float bf2f(unsigned short h) {
  return __builtin_bit_cast(float, (unsigned)h << 16);
}

__device__ __forceinline__ void async16(const void* g, void* l) {
  __builtin_amdgcn_global_load_lds((gas_ptr)g, (las_ptr)l, 16, 0, 0);
}

// ---------------- prep: cast + pad X0 to [rows][128] bf16 ----------------
__global__ void prep_x0(const float* __restrict__ xx, unsigned short* __restrict__ X0,
                        int rowOffset, int rows) {
  int idx = blockIdx.x * blockDim.x + threadIdx.x;
  if (idx >= rows * 128) return;
  int r = idx >> 7, c = idx & 127;
  float v = (c < 80) ? xx[(size_t)(rowOffset + r) * 80 + c] : 0.f;
  X0[(size_t)r * 128 + c] = f2bf(v);
}

// ---------------- prep: W [K][N] fp32 -> WT [N][KP] bf16 (pad K) ----------
__global__ void transpose_cast(const float* __restrict__ W, unsigned short* __restrict__ WT,
                               int K, int N, int KP) {
  __shared__ float tile[32][33];
  int n0 = blockIdx.x * 32, k0 = blockIdx.y * 32;
  int tx = threadIdx.x, ty = threadIdx.y;
  #pragma unroll
  for (int j = 0; j < 32; j += 8) {
    int k = k0 + ty + j;
    tile[ty + j][tx] = (k < K) ? W[(size_t)k * N + n0 + tx] : 0.f;
  }
  __syncthreads();
  #pragma unroll
  for (int j = 0; j < 32; j += 8) {
    WT[(size_t)(n0 + ty + j) * KP + k0 + tx] = f2bf(tile[tx][ty + j]);
  }
}

// ---------------- small GEMM (layer 0, K=128): m97 structure --------------
#define BM 128
#define BN 128
#define BK 64

__global__ void gemm_mlp(const unsigned short* __restrict__ A,
                         const unsigned short* __restrict__ BT,
                         const float* __restrict__ bias,
                         unsigned short* __restrict__ C,
                         int M, int N, int K, int leaky) {
  __shared__ unsigned short As[BM * BK];
  __shared__ unsigned short Bs[BN * BK];

  const int tid  = threadIdx.x;
  const int wid  = tid >> 6;
  const int lane = tid & 63;
  const int wr = (wid >> 1) * 64;
  const int wc = (wid & 1) * 64;
  const int bn = blockIdx.x * BN;
  const int bm = blockIdx.y * BM;

  const int srow = lane >> 3;
  const int scol = (lane & 7) * 8;

  f32x4 acc[4][4] = {};

  const unsigned short* aTile = A  + (size_t)bm * K;
  const unsigned short* bTile = BT + (size_t)bn * K;

  for (int k0 = 0; k0 < K; k0 += BK) {
    #pragma unroll
    for (int j = 0; j < 4; ++j) {
      const int rg = wid + j * 4;
      async16(aTile + (size_t)(rg * 8 + srow) * K + k0 + scol, &As[rg * 8 * BK]);
      async16(bTile + (size_t)(rg * 8 + srow) * K + k0 + scol, &Bs[rg * 8 * BK]);
    }
    __syncthreads();

    const int fr = lane & 15;
    const int kq = (lane >> 4) * 8;
    #pragma unroll
    for (int ks = 0; ks < BK; ks += 32) {
      const int kk = ks + kq;
      bf16x8 af[4], bv[4];
      #pragma unroll
      for (int m = 0; m < 4; ++m)
        af[m] = __builtin_bit_cast(bf16x8, *(const s16x8*)&As[(wr + m * 16 + fr) * BK + kk]);
      #pragma unroll
      for (int n = 0; n < 4; ++n)
        bv[n] = __builtin_bit_cast(bf16x8, *(const s16x8*)&Bs[(wc + n * 16 + fr) * BK + kk]);
      #pragma unroll
      for (int m = 0; m < 4; ++m)
        #pragma unroll
        for (int n = 0; n < 4; ++n)
          acc[m][n] = __builtin_amdgcn_mfma_f32_16x16x32_bf16(af[m], bv[n], acc[m][n], 0, 0, 0);
    }
    __syncthreads();
  }

  const int fcol = lane & 15;
  const int frow = (lane >> 4) * 4;
  #pragma unroll
  for (int m = 0; m < 4; ++m) {
    #pragma unroll
    for (int n = 0; n < 4; ++n) {
      const int col = bn + wc + n * 16 + fcol;
      const float bb = bias[col];
      #pragma unroll
      for (int r = 0; r < 4; ++r) {
        const int row = bm + wr + m * 16 + frow + r;
        float v = acc[m][n][r] + bb;
        if (leaky) v = (v > 0.f) ? v : 0.01f * v;
        C[(size_t)row * N + col] = f2bf(v);
      }
    }
  }
}

// ---------------- 256x256x64 8-phase GEMM (layers 1-5, K=1024) ------------
// 8 waves (2M x 4N), per-wave 128x64 output. LDS 128 KiB dbuf.
// XOR swizzle: 16B slot s of row r holds global unit s ^ (r&7).
// Staging: ALL four half-tiles of tile kt+2 staged during tile kt
// (SB0 at P2, SB1+SA0+SA1 at P3) into buffer c -- legal because B-reads of
// buf c end at P1's pre-MFMA barrier and A-reads end at P2's pre-MFMA
// barrier, and stages are issued only after the following post-MFMA barrier.
// vmcnt ledger: at end of tile kt, outstanding = T(kt+1)[8] + T(kt+2)[8];
// vmcnt(8) drains exactly T(kt+1) (one full tile of HBM latency cover).

__device__ __forceinline__ void stage_half(const char* srcRow0, size_t ldb,
                                           char* ldsHalf, int w, int rsub, int usw) {
  #pragma unroll
  for (int l = 0; l < 2; ++l) {
    const char* src = srcRow0 + (size_t)((l * 8 + w) * 8 + rsub) * ldb + usw;
    async16(src, ldsHalf + (l * 8 + w) * 1024);
  }
}

#define MFMA16 __builtin_amdgcn_mfma_f32_16x16x32_bf16

__global__ __launch_bounds__(512, 2)
void gemm8(const unsigned short* __restrict__ A,
           const unsigned short* __restrict__ BT,
           const float* __restrict__ bias,
           unsigned short* __restrict__ C,
           int M, int N, int K) {
  extern __shared__ char smem[];
  char* smA = smem;             // [2][32768] bytes
  char* smB = smem + 65536;     // [2][32768] bytes
  const unsigned short* sA = (const unsigned short*)smA;
  const unsigned short* sB = (const unsigned short*)smB;
  const int NTk = K >> 6;

  const int tid  = threadIdx.x;
  const int w    = tid >> 6;
  const int lane = tid & 63;

  // bijective XCD-chunked block swizzle (m204)
  const int nwg = gridDim.x;
  const int bid = blockIdx.x;
  const int q = nwg >> 3, r = nwg & 7;
  const int xcd = bid & 7, idx = bid >> 3;
  const int wg = (xcd < r ? xcd * (q + 1) : r * (q + 1) + (xcd - r) * q) + idx;
  const int nNT = N >> 8;
  const int mtile = wg / nNT, ntile = wg % nNT;   // N fastest
  const int bm = mtile << 8, bn = ntile << 8;

  const int wr = (w >> 2) << 7;      // 0 / 128
  const int wc = (w & 3) << 6;       // 0/64/128/192
  const int fr = lane & 15;
  const int e0 = lane >> 4;
  const int sw = lane & 7;
  const int rsub = lane >> 3;
  const int usw  = ((sw ^ rsub) << 4);         // pre-swizzled global unit offset
  const int col0 = (((e0)     ^ sw) << 3);     // swizzled LDS element offset, ks=0
  const int col1 = (((e0 + 4) ^ sw) << 3);     // ks=32

  const size_t ldb = (size_t)K * 2;
  const char* Ab = (const char*)A  + (size_t)bm * ldb;
  const char* Bb = (const char*)BT + (size_t)bn * ldb;

  f32x4 acc[8][4] = {};

#define RDA(c_, row_, col_) __builtin_bit_cast(bf16x8, *(const s16x8*)&sA[(c_) * 16384 + (row_) * 64 + (col_)])
#define RDB(c_, row_, col_) __builtin_bit_cast(bf16x8, *(const s16x8*)&sB[(c_) * 16384 + (row_) * 64 + (col_)])

  // ---- prologue: tile0 fully, then tile1 fully (issue order = vmcnt order)
  stage_half(Bb,                    ldb, smB,                  w, rsub, usw);  // SB0(0)
  stage_half(Bb + 128 * ldb,        ldb, smB + 16384,          w, rsub, usw);  // SB1(0)
  stage_half(Ab,                    ldb, smA,                  w, rsub, usw);  // SA0(0)
  stage_half(Ab + 128 * ldb,        ldb, smA + 16384,          w, rsub, usw);  // SA1(0)
  stage_half(Bb + 128,              ldb, smB + 32768,          w, rsub, usw);  // SB0(1)
  stage_half(Bb + 128 * ldb + 128,  ldb, smB + 32768 + 16384,  w, rsub, usw);  // SB1(1)
  stage_half(Ab + 128,              ldb, smA + 32768,          w, rsub, usw);  // SA0(1)
  stage_half(Ab + 128 * ldb + 128,  ldb, smA + 32768 + 16384,  w, rsub, usw);  // SA1(1)
  asm volatile("s_waitcnt vmcnt(8)" ::: "memory");   // tile0 complete
  __builtin_amdgcn_s_barrier();

  for (int kt = 0; kt < NTk; ++kt) {
    const int c = kt & 1;
    bf16x8 aF[4][2], bF[4][2];

    // ---------- P0: A(m0-3) + B(n0-1) reads; Q0
    #pragma unroll
    for (int m = 0; m < 4; ++m) {
      const int row = wr + m * 16 + fr;
      aF[m][0] = RDA(c, row, col0);
      aF[m][1] = RDA(c, row, col1);
    }
    #pragma unroll
    for (int n = 0; n < 2; ++n) {
      const int row = wc + n * 16 + fr;
      bF[n][0] = RDB(c, row, col0);
      bF[n][1] = RDB(c, row, col1);
    }
    __builtin_amdgcn_s_barrier();
    __builtin_amdgcn_s_setprio(1);
    #pragma unroll
    for (int m = 0; m < 4; ++m)
      #pragma unroll
      for (int n = 0; n < 2; ++n) {
        acc[m][n] = MFMA16(aF[m][0], bF[n][0], acc[m][n], 0, 0, 0);
        acc[m][n] = MFMA16(aF[m][1], bF[n][1], acc[m][n], 0, 0, 0);
      }
    __builtin_amdgcn_s_setprio(0);
    __builtin_amdgcn_s_barrier();

    // ---------- P1: B(n2-3) reads; Q1   (B-reads of buf c end here)
    #pragma unroll
    for (int n = 2; n < 4; ++n) {
      const int row = wc + n * 16 + fr;
      bF[n][0] = RDB(c, row, col0);
      bF[n][1] = RDB(c, row, col1);
    }
    __builtin_amdgcn_s_barrier();
    __builtin_amdgcn_s_setprio(1);
    #pragma unroll
    for (int m = 0; m < 4; ++m)
      #pragma unroll
      for (int n = 2; n < 4; ++n) {
        acc[m][n] = MFMA16(aF[m][0], bF[n][0], acc[m][n], 0, 0, 0);
        acc[m][n] = MFMA16(aF[m][1], bF[n][1], acc[m][n], 0, 0, 0);
      }
    __builtin_amdgcn_s_setprio(0);
    __builtin_amdgcn_s_barrier();

    // ---------- P2: A(m4-7) reads; stage SB0(kt+2) into buf c; Q2
    #pragma unroll
    for (int m = 0; m < 4; ++m) {
      const int row = wr + (m + 4) * 16 + fr;
      aF[m][0] = RDA(c, row, col0);
      aF[m][1] = RDA(c, row, col1);
    }
    if (kt + 2 < NTk)
      stage_half(Bb + (size_t)(kt + 2) * 128, ldb, smB + c * 32768, w, rsub, usw);
    __builtin_amdgcn_s_barrier();
    __builtin_amdgcn_s_setprio(1);
    #pragma unroll
    for (int m = 0; m < 4; ++m)
      #pragma unroll
      for (int n = 0; n < 2; ++n) {
        acc[m + 4][n] = MFMA16(aF[m][0], bF[n][0], acc[m + 4][n], 0, 0, 0);
        acc[m + 4][n] = MFMA16(aF[m][1], bF[n][1], acc[m + 4][n], 0, 0, 0);
      }
    __builtin_amdgcn_s_setprio(0);
    __builtin_amdgcn_s_barrier();

    // ---------- P3: stage SB1(kt+2) + SA0(kt+2) + SA1(kt+2) into buf c; Q3
    if (kt + 2 < NTk) {
      stage_half(Bb + 128 * ldb + (size_t)(kt + 2) * 128, ldb,
                 smB + c * 32768 + 16384, w, rsub, usw);
      stage_half(Ab + (size_t)(kt + 2) * 128, ldb, smA + c * 32768, w, rsub, usw);
      stage_half(Ab + 128 * ldb + (size_t)(kt + 2) * 128, ldb,
                 smA + c * 32768 + 16384, w, rsub, usw);
    }
    __builtin_amdgcn_s_barrier();
    __builtin_amdgcn_s_setprio(1);
    #pragma unroll
    for (int m = 0; m < 4; ++m)
      #pragma unroll
      for (int n = 2; n < 4; ++n) {
        acc[m + 4][n] = MFMA16(aF[m][0], bF[n][0], acc[m + 4][n], 0, 0, 0);
        acc[m + 4][n] = MFMA16(aF[m][1], bF[n][1], acc[m + 4][n], 0, 0, 0);
      }
    __builtin_amdgcn_s_setprio(0);
    if (kt + 2 < NTk) asm volatile("s_waitcnt vmcnt(8)" ::: "memory");
    else              asm volatile("s_waitcnt vmcnt(0)" ::: "memory");
    __builtin_amdgcn_s_barrier();
  }

#undef RDA
#undef RDB

  // ---- epilogue: bias + leaky, bf16 store
  const int fcol = lane & 15;
  const int frow = e0 << 2;
  #pragma unroll
  for (int n = 0; n < 4; ++n) {
    const int col = bn + wc + n * 16 + fcol;
    const float bb = bias[col];
    #pragma unroll
    for (int m = 0; m < 8; ++m) {
      #pragma unroll
      for (int rr = 0; rr < 4; ++rr) {
        const int row = bm + wr + m * 16 + frow + rr;
        float v = acc[m][n][rr] + bb;
        v = (v > 0.f) ? v : 0.01f * v;
        C[(size_t)row * N + col] = f2bf(v);
      }
    }
  }
}

// ---------------- head GEMV: beta/gamma/sigma per row ---------------------
__global__ void head_gemv(const unsigned short* __restrict__ H,
                          const float* __restrict__ W6,
                          const float* __restrict__ b6,
                          float* __restrict__ bgs,
                          int rows) {
  const int w = (blockIdx.x * blockDim.x + threadIdx.x) >> 6;
  const int lane = threadIdx.x & 63;
  if (w >= rows) return;

  const unsigned short* h = H + (size_t)w * 1024 + lane * 16;
  float s0 = 0.f, s1 = 0.f, s2 = 0.f;
  #pragma unroll
  for (int i = 0; i < 16; i += 8) {
    s16x8 v = *(const s16x8*)(h + i);
    #pragma unroll
    for (int j = 0; j < 8; ++j) {
      const float hv = bf2f((unsigned short)v[j]);
      const int e = lane * 16 + i + j;
      s0 = fmaf(hv, W6[e * 3 + 0], s0);
      s1 = fmaf(hv, W6[e * 3 + 1], s1);
      s2 = fmaf(hv, W6[e * 3 + 2], s2);
    }
  }
  #pragma unroll
  for (int off = 1; off < 64; off <<= 1) {
    s0 += __shfl_xor(s0, off);
    s1 += __shfl_xor(s1, off);
    s2 += __shfl_xor(s2, off);
  }
  if (lane == 0) {
    float4 v = make_float4(s0 + b6[0], s1 + b6[1], s2 + b6[2], 0.f);
    *(float4*)(bgs + (size_t)w * 4) = v;
  }
}

// ---------------- RK4 SEIR: one thread per row ----------------------------
__global__ void rk4_traj(const float* __restrict__ bgs,
                         const float* __restrict__ xx,
                         float* __restrict__ out,
                         int rowOffset, int rows, int T) {
  const int r = blockIdx.x * blockDim.x + threadIdx.x;
  if (r >= rows) return;
  const size_t grow = (size_t)rowOffset + r;

  const float4 bg = *(const float4*)(bgs + (size_t)r * 4);
  const float beta = bg.x, gamma = bg.y, sigma = bg.z;

  const float4 iv = *(const float4*)(xx + grow * 80);
  float S = iv.x, E = iv.y, I = iv.z, R = iv.w;
  float* o = out + grow * (size_t)T * 4;
  *(float4*)o = iv;

#define DERIVS(S_, E_, I_, dS, dE, dI, dR)      \
  {                                             \
    float SI = beta * (S_) * (I_);              \
    float sE = sigma * (E_);                    \
    float gI = gamma * (I_);                    \
    dS = -SI; dE = SI - sE; dI = sE - gI; dR = gI; \
  }

  for (int t = 1; t < T; ++t) {
    float k1S, k1E, k1I, k1R; DERIVS(S, E, I, k1S, k1E, k1I, k1R);
    float k2S, k2E, k2I, k2R; DERIVS(S + 0.5f * k1S, E + 0.5f * k1E, I + 0.5f * k1I, k2S, k2E, k2I, k2R);
    float k3S, k3E, k3I, k3R; DERIVS(S + 0.5f * k2S, E + 0.5f * k2E, I + 0.5f * k2I, k3S, k3E, k3I, k3R);
    float k4S, k4E, k4I, k4R; DERIVS(S + k3S, E + k3E, I + k3I, k4S, k4E, k4I, k4R);
    S += (k1S + 2.f * k2S + 2.f * k3S + k4S) * (1.f / 6.f);
    E += (k1E + 2.f * k2E + 2.f * k3E + k4E) * (1.f / 6.f);
    I += (k1I + 2.f * k2I + 2.f * k3I + k4I) * (1.f / 6.f);
    R += (k1R + 2.f * k2R + 2.f * k3R + k4R) * (1.f / 6.f);
    *(float4*)(o + (size_t)t * 4) = make_float4(S, E, I, R);
  }
#undef DERIVS
}

// --------------------------------------------------------------------------
extern "C" void kernel_launch(void* const* d_in, const int* in_sizes, int n_in,
                              void* d_out, int out_size, void* d_ws, size_t ws_size,
                              hipStream_t stream) {
  const float* xx = (const float*)d_in[0];
  const float* W[7];
  const float* bb[7];
  for (int i = 0; i < 7; ++i) {
    W[i]  = (const float*)d_in[1 + 2 * i];
    bb[i] = (const float*)d_in[2 + 2 * i];
  }
  const int B = in_sizes[0] / 80;
  const int T = out_size / (B * 4);
  float* out = (float*)d_out;

  hipFuncSetAttribute((const void*)gemm8,
                      hipFuncAttributeMaxDynamicSharedMemorySize, 131072);

  uint8_t* ws = (uint8_t*)d_ws;
  size_t off = 0;
  auto alloc = [&](size_t bytes) -> uint8_t* {
    uint8_t* p = ws + off;
    off += (bytes + 255) & ~(size_t)255;
    return p;
  };

  unsigned short* WTl[6];
  WTl[0] = (unsigned short*)alloc((size_t)1024 * 128 * 2);
  for (int i = 1; i < 6; ++i) WTl[i] = (unsigned short*)alloc((size_t)1024 * 1024 * 2);

  const size_t weightBytes = off;
  const size_t avail = ws_size > weightBytes ? ws_size - weightBytes : 0;
  int Bc = (int)(avail / 4368);  // per-row: 128*2 (X0) + 2*1024*2 (ping-pong) + 16 (bgs)
  Bc = (Bc / 256) * 256;
  if (Bc > B) Bc = B;
  if (Bc < 256) Bc = 256;

  unsigned short* X0   = (unsigned short*)alloc((size_t)Bc * 128 * 2);
  unsigned short* buf0 = (unsigned short*)alloc((size_t)Bc * 1024 * 2);
  unsigned short* buf1 = (unsigned short*)alloc((size_t)Bc * 1024 * 2);
  float* bgs           = (float*)alloc((size_t)Bc * 4 * 4);

  // one-time weight transposes (bf16)
  {
    dim3 blk(32, 8);
    transpose_cast<<<dim3(32, 4), blk, 0, stream>>>(W[0], WTl[0], 80, 1024, 128);
    for (int i = 1; i < 6; ++i)
      transpose_cast<<<dim3(32, 32), blk, 0, stream>>>(W[i], WTl[i], 1024, 1024, 1024);
  }

  for (int r0 = 0; r0 < B; r0 += Bc) {
    const int rows = (B - r0 < Bc) ? (B - r0) : Bc;

    {
      const int n = rows * 128;
      prep_x0<<<(n + 255) / 256, 256, 0, stream>>>(xx, X0, r0, rows);
    }

    // layer 0: K=128, m97-structure kernel
    gemm_mlp<<<dim3(8, rows / 128), 256, 0, stream>>>(X0, WTl[0], bb[0], buf0,
                                                      rows, 1024, 128, 1);

    // layers 1-5: 256^2 8-phase kernel
    const int nwg = (rows / 256) * 4;
    gemm8<<<nwg, 512, 131072, stream>>>(buf0, WTl[1], bb[1], buf1, rows, 1024, 1024);
    gemm8<<<nwg, 512, 131072, stream>>>(buf1, WTl[2], bb[2], buf0, rows, 1024, 1024);
    gemm8<<<nwg, 512, 131072, stream>>>(buf0, WTl[3], bb[3], buf1, rows, 1024, 1024);
    gemm8<<<nwg, 512, 131072, stream>>>(buf1, WTl[4], bb[4], buf0, rows, 1024, 1024);
    gemm8<<<nwg, 512, 131072, stream>>>(buf0, WTl[5], bb[5], buf1, rows, 1024, 1024);

    head_gemv<<<rows / 4, 256, 0, stream>>>(buf1, W[6], bb[6], bgs, rows);
    rk4_traj<<<(rows + 255) / 256, 256, 0, stream>>>(bgs, xx, out, r0, rows, T);
  }
}

// Round 8
// 1011.505 us; speedup vs baseline: 1.1293x; 1.1293x over previous
//
#include <hip/hip_runtime.h>
#include <stdint.h>

typedef short s16x8 __attribute__((ext_vector_type(8)));
typedef __bf16 bf16x8 __attribute__((ext_vector_type(8)));
typedef float f32x4 __attribute__((ext_vector_type(4)));

typedef const __attribute__((address_space(1))) void* gas_ptr;
typedef __attribute__((address_space(3))) void* las_ptr;

__device__ __forceinline__ unsigned short f2bf(float f) {
  unsigned u = __builtin_bit_cast(unsigned, f);
  u += 0x7FFFu + ((u >> 16) & 1u);   // round-to-nearest-even
  return (unsigned short)(u >> 16);
}
__device__ __forceinline__ float bf2f(unsigned short h) {
  return __builtin_bit_cast(float, (unsigned)h << 16);
}
__device__ __forceinline__ void async16(const void* g, void* l) {
  __builtin_amdgcn_global_load_lds((gas_ptr)g, (las_ptr)l, 16, 0, 0);
}

// ---------------- prep: cast + pad X0 to [rows][128] bf16 ----------------
__global__ void prep_x0(const float* __restrict__ xx, unsigned short* __restrict__ X0,
                        int rowOffset, int rows) {
  int idx = blockIdx.x * blockDim.x + threadIdx.x;
  if (idx >= rows * 128) return;
  int r = idx >> 7, c = idx & 127;
  float v = (c < 80) ? xx[(size_t)(rowOffset + r) * 80 + c] : 0.f;
  X0[(size_t)r * 128 + c] = f2bf(v);
}

// ---------------- prep: W [K][N] fp32 -> WT [N][KP] bf16 (pad K) ----------
__global__ void transpose_cast(const float* __restrict__ W, unsigned short* __restrict__ WT,
                               int K, int N, int KP) {
  __shared__ float tile[32][33];
  int n0 = blockIdx.x * 32, k0 = blockIdx.y * 32;
  int tx = threadIdx.x, ty = threadIdx.y;
  #pragma unroll
  for (int j = 0; j < 32; j += 8) {
    int k = k0 + ty + j;
    tile[ty + j][tx] = (k < K) ? W[(size_t)k * N + n0 + tx] : 0.f;
  }
  __syncthreads();
  #pragma unroll
  for (int j = 0; j < 32; j += 8) {
    WT[(size_t)(n0 + ty + j) * KP + k0 + tx] = f2bf(tile[tx][ty + j]);
  }
}

// ---------------- small GEMM (layer 0, K=128): m97 structure --------------
#define BM 128
#define BN 128
#define BK 64

__global__ void gemm_mlp(const unsigned short* __restrict__ A,
                         const unsigned short* __restrict__ BT,
                         const float* __restrict__ bias,
                         unsigned short* __restrict__ C,
                         int M, int N, int K, int leaky) {
  __shared__ unsigned short As[BM * BK];
  __shared__ unsigned short Bs[BN * BK];

  const int tid  = threadIdx.x;
  const int wid  = tid >> 6;
  const int lane = tid & 63;
  const int wr = (wid >> 1) * 64;
  const int wc = (wid & 1) * 64;
  const int bn = blockIdx.x * BN;
  const int bm = blockIdx.y * BM;

  const int srow = lane >> 3;
  const int scol = (lane & 7) * 8;

  f32x4 acc[4][4] = {};

  const unsigned short* aTile = A  + (size_t)bm * K;
  const unsigned short* bTile = BT + (size_t)bn * K;

  for (int k0 = 0; k0 < K; k0 += BK) {
    #pragma unroll
    for (int j = 0; j < 4; ++j) {
      const int rg = wid + j * 4;
      async16(aTile + (size_t)(rg * 8 + srow) * K + k0 + scol, &As[rg * 8 * BK]);
      async16(bTile + (size_t)(rg * 8 + srow) * K + k0 + scol, &Bs[rg * 8 * BK]);
    }
    __syncthreads();

    const int fr = lane & 15;
    const int kq = (lane >> 4) * 8;
    #pragma unroll
    for (int ks = 0; ks < BK; ks += 32) {
      const int kk = ks + kq;
      bf16x8 af[4], bv[4];
      #pragma unroll
      for (int m = 0; m < 4; ++m)
        af[m] = __builtin_bit_cast(bf16x8, *(const s16x8*)&As[(wr + m * 16 + fr) * BK + kk]);
      #pragma unroll
      for (int n = 0; n < 4; ++n)
        bv[n] = __builtin_bit_cast(bf16x8, *(const s16x8*)&Bs[(wc + n * 16 + fr) * BK + kk]);
      #pragma unroll
      for (int m = 0; m < 4; ++m)
        #pragma unroll
        for (int n = 0; n < 4; ++n)
          acc[m][n] = __builtin_amdgcn_mfma_f32_16x16x32_bf16(af[m], bv[n], acc[m][n], 0, 0, 0);
    }
    __syncthreads();
  }

  const int fcol = lane & 15;
  const int frow = (lane >> 4) * 4;
  #pragma unroll
  for (int m = 0; m < 4; ++m) {
    #pragma unroll
    for (int n = 0; n < 4; ++n) {
      const int col = bn + wc + n * 16 + fcol;
      const float bb = bias[col];
      #pragma unroll
      for (int r = 0; r < 4; ++r) {
        const int row = bm + wr + m * 16 + frow + r;
        float v = acc[m][n][r] + bb;
        if (leaky) v = (v > 0.f) ? v : 0.01f * v;
        C[(size_t)row * N + col] = f2bf(v);
      }
    }
  }
}

// ---------------- 256x256x64 8-phase GEMM (layers 1-5, K=1024) ------------
// Schedule = the round-3-benched variant (175us): SA(kt+1) staged at P0/P1,
// SB(kt+2) at P2/P3, vmcnt(4) once per K-tile.
// New: LDS-staged vectorized epilogue (EPAD=72 -> all ds_read_b128 aligned,
// per-wave-private 9216B region, full 128B global store segments).

__device__ __forceinline__ void stage_half(const char* srcRow0, size_t ldb,
                                           char* ldsHalf, int w, int rsub, int usw) {
  #pragma unroll
  for (int l = 0; l < 2; ++l) {
    const char* src = srcRow0 + (size_t)((l * 8 + w) * 8 + rsub) * ldb + usw;
    async16(src, ldsHalf + (l * 8 + w) * 1024);
  }
}

#define MFMA16 __builtin_amdgcn_mfma_f32_16x16x32_bf16
#define EPAD 72
#define EBYTES (64 * EPAD * 2)   // 9216 B per wave

__global__ __launch_bounds__(512, 2)
void gemm8(const unsigned short* __restrict__ A,
           const unsigned short* __restrict__ BT,
           const float* __restrict__ bias,
           unsigned short* __restrict__ C,
           int M, int N, int K) {
  extern __shared__ char smem[];
  char* smA = smem;             // [2][32768]
  char* smB = smem + 65536;     // [2][32768]
  const unsigned short* sA = (const unsigned short*)smA;
  const unsigned short* sB = (const unsigned short*)smB;
  const int NTk = K >> 6;

  const int tid  = threadIdx.x;
  const int w    = tid >> 6;
  const int lane = tid & 63;

  // bijective XCD-chunked block swizzle (m204)
  const int nwg = gridDim.x;
  const int bid = blockIdx.x;
  const int q = nwg >> 3, r = nwg & 7;
  const int xcd = bid & 7, idx = bid >> 3;
  const int wg = (xcd < r ? xcd * (q + 1) : r * (q + 1) + (xcd - r) * q) + idx;
  const int nNT = N >> 8;
  const int mtile = wg / nNT, ntile = wg % nNT;   // N fastest
  const int bm = mtile << 8, bn = ntile << 8;

  const int wr = (w >> 2) << 7;      // 0 / 128
  const int wc = (w & 3) << 6;       // 0/64/128/192
  const int fr = lane & 15;
  const int e0 = lane >> 4;
  const int sw = lane & 7;
  const int rsub = lane >> 3;
  const int usw  = ((sw ^ rsub) << 4);         // pre-swizzled global unit offset
  const int col0 = (((e0)     ^ sw) << 3);     // swizzled LDS element offset, ks=0
  const int col1 = (((e0 + 4) ^ sw) << 3);     // ks=32

  const size_t ldb = (size_t)K * 2;
  const char* Ab = (const char*)A  + (size_t)bm * ldb;
  const char* Bb = (const char*)BT + (size_t)bn * ldb;

  f32x4 acc[8][4] = {};

#define RDA(c_, row_, col_) __builtin_bit_cast(bf16x8, *(const s16x8*)&sA[(c_) * 16384 + (row_) * 64 + (col_)])
#define RDB(c_, row_, col_) __builtin_bit_cast(bf16x8, *(const s16x8*)&sB[(c_) * 16384 + (row_) * 64 + (col_)])

  // prologue: tile0 fully, tile1 B-halves (A(1) staged in kt=0 P0/P1)
  stage_half(Bb,                    ldb, smB,                  w, rsub, usw);  // SB0(0)
  stage_half(Bb + 128 * ldb,        ldb, smB + 16384,          w, rsub, usw);  // SB1(0)
  stage_half(Ab,                    ldb, smA,                  w, rsub, usw);  // SA0(0)
  stage_half(Ab + 128 * ldb,        ldb, smA + 16384,          w, rsub, usw);  // SA1(0)
  stage_half(Bb + 128,              ldb, smB + 32768,          w, rsub, usw);  // SB0(1)
  stage_half(Bb + 128 * ldb + 128,  ldb, smB + 32768 + 16384,  w, rsub, usw);  // SB1(1)
  asm volatile("s_waitcnt vmcnt(4)" ::: "memory");   // tile0 complete
  __builtin_amdgcn_s_barrier();

  for (int kt = 0; kt < NTk; ++kt) {
    const int c = kt & 1;
    bf16x8 aF[4][2], bF[4][2];

    // P0: A(m0-3)+B(n0-1) reads; stage SA0(kt+1); Q0
    #pragma unroll
    for (int m = 0; m < 4; ++m) {
      const int row = wr + m * 16 + fr;
      aF[m][0] = RDA(c, row, col0);
      aF[m][1] = RDA(c, row, col1);
    }
    #pragma unroll
    for (int n = 0; n < 2; ++n) {
      const int row = wc + n * 16 + fr;
      bF[n][0] = RDB(c, row, col0);
      bF[n][1] = RDB(c, row, col1);
    }
    if (kt + 1 < NTk)
      stage_half(Ab + (size_t)(kt + 1) * 128, ldb, smA + (c ^ 1) * 32768, w, rsub, usw);
    __builtin_amdgcn_s_barrier();
    __builtin_amdgcn_s_setprio(1);
    #pragma unroll
    for (int m = 0; m < 4; ++m)
      #pragma unroll
      for (int n = 0; n < 2; ++n) {
        acc[m][n] = MFMA16(aF[m][0], bF[n][0], acc[m][n], 0, 0, 0);
        acc[m][n] = MFMA16(aF[m][1], bF[n][1], acc[m][n], 0, 0, 0);
      }
    __builtin_amdgcn_s_setprio(0);
    __builtin_amdgcn_s_barrier();

    // P1: B(n2-3) reads; stage SA1(kt+1); Q1
    #pragma unroll
    for (int n = 2; n < 4; ++n) {
      const int row = wc + n * 16 + fr;
      bF[n][0] = RDB(c, row, col0);
      bF[n][1] = RDB(c, row, col1);
    }
    if (kt + 1 < NTk)
      stage_half(Ab + 128 * ldb + (size_t)(kt + 1) * 128, ldb,
                 smA + (c ^ 1) * 32768 + 16384, w, rsub, usw);
    __builtin_amdgcn_s_barrier();
    __builtin_amdgcn_s_setprio(1);
    #pragma unroll
    for (int m = 0; m < 4; ++m)
      #pragma unroll
      for (int n = 2; n < 4; ++n) {
        acc[m][n] = MFMA16(aF[m][0], bF[n][0], acc[m][n], 0, 0, 0);
        acc[m][n] = MFMA16(aF[m][1], bF[n][1], acc[m][n], 0, 0, 0);
      }
    __builtin_amdgcn_s_setprio(0);
    __builtin_amdgcn_s_barrier();

    // P2: A(m4-7) reads; stage SB0(kt+2); Q2
    #pragma unroll
    for (int m = 0; m < 4; ++m) {
      const int row = wr + (m + 4) * 16 + fr;
      aF[m][0] = RDA(c, row, col0);
      aF[m][1] = RDA(c, row, col1);
    }
    if (kt + 2 < NTk)
      stage_half(Bb + (size_t)(kt + 2) * 128, ldb, smB + c * 32768, w, rsub, usw);
    __builtin_amdgcn_s_barrier();
    __builtin_amdgcn_s_setprio(1);
    #pragma unroll
    for (int m = 0; m < 4; ++m)
      #pragma unroll
      for (int n = 0; n < 2; ++n) {
        acc[m + 4][n] = MFMA16(aF[m][0], bF[n][0], acc[m + 4][n], 0, 0, 0);
        acc[m + 4][n] = MFMA16(aF[m][1], bF[n][1], acc[m + 4][n], 0, 0, 0);
      }
    __builtin_amdgcn_s_setprio(0);
    __builtin_amdgcn_s_barrier();

    // P3: stage SB1(kt+2); Q3; counted vmcnt
    if (kt + 2 < NTk)
      stage_half(Bb + 128 * ldb + (size_t)(kt + 2) * 128, ldb,
                 smB + c * 32768 + 16384, w, rsub, usw);
    __builtin_amdgcn_s_barrier();
    __builtin_amdgcn_s_setprio(1);
    #pragma unroll
    for (int m = 0; m < 4; ++m)
      #pragma unroll
      for (int n = 2; n < 4; ++n) {
        acc[m + 4][n] = MFMA16(aF[m][0], bF[n][0], acc[m + 4][n], 0, 0, 0);
        acc[m + 4][n] = MFMA16(aF[m][1], bF[n][1], acc[m + 4][n], 0, 0, 0);
      }
    __builtin_amdgcn_s_setprio(0);
    if (kt + 2 < NTk) asm volatile("s_waitcnt vmcnt(4)" ::: "memory");
    else              asm volatile("s_waitcnt vmcnt(0)" ::: "memory");
    __builtin_amdgcn_s_barrier();
  }

#undef RDA
#undef RDB

  // epilogue: per-wave LDS transpose -> vectorized bf16 stores (128B segments)
  unsigned short* eb = (unsigned short*)(smem + w * EBYTES);  // [64][EPAD] bf16
  const int fcol = lane & 15;
  float bbv[4];
  #pragma unroll
  for (int n = 0; n < 4; ++n) bbv[n] = bias[bn + wc + n * 16 + fcol];
  const int r8 = lane >> 3, c8 = (lane & 7) * 8;
  #pragma unroll
  for (int mh = 0; mh < 2; ++mh) {
    #pragma unroll
    for (int mm = 0; mm < 4; ++mm)
      #pragma unroll
      for (int n = 0; n < 4; ++n)
        #pragma unroll
        for (int rr = 0; rr < 4; ++rr) {
          const int row64 = mm * 16 + e0 * 4 + rr;
          float v = acc[mh * 4 + mm][n][rr] + bbv[n];
          v = (v > 0.f) ? v : 0.01f * v;
          eb[row64 * EPAD + n * 16 + fcol] = f2bf(v);
        }
    asm volatile("" ::: "memory");
    #pragma unroll
    for (int rg = 0; rg < 8; ++rg) {
      const int row64 = rg * 8 + r8;
      s16x8 vv = *(const s16x8*)&eb[row64 * EPAD + c8];
      const int rl = bm + wr + mh * 64 + row64;
      *(s16x8*)&C[(size_t)rl * N + bn + wc + c8] = vv;
    }
    asm volatile("" ::: "memory");
  }
}

// ---------------- head GEMV: beta/gamma/sigma per row ---------------------
__global__ void head_gemv(const unsigned short* __restrict__ H,
                          const float* __restrict__ W6,
                          const float* __restrict__ b6,
                          float* __restrict__ bgs,
                          int rows) {
  const int w = (blockIdx.x * blockDim.x + threadIdx.x) >> 6;
  const int lane = threadIdx.x & 63;
  if (w >= rows) return;

  const unsigned short* h = H + (size_t)w * 1024 + lane * 16;
  float s0 = 0.f, s1 = 0.f, s2 = 0.f;
  #pragma unroll
  for (int i = 0; i < 16; i += 8) {
    s16x8 v = *(const s16x8*)(h + i);
    #pragma unroll
    for (int j = 0; j < 8; ++j) {
      const float hv = bf2f((unsigned short)v[j]);
      const int e = lane * 16 + i + j;
      s0 = fmaf(hv, W6[e * 3 + 0], s0);
      s1 = fmaf(hv, W6[e * 3 + 1], s1);
      s2 = fmaf(hv, W6[e * 3 + 2], s2);
    }
  }
  #pragma unroll
  for (int off = 1; off < 64; off <<= 1) {
    s0 += __shfl_xor(s0, off);
    s1 += __shfl_xor(s1, off);
    s2 += __shfl_xor(s2, off);
  }
  if (lane == 0) {
    float4 v = make_float4(s0 + b6[0], s1 + b6[1], s2 + b6[2], 0.f);
    *(float4*)(bgs + (size_t)w * 4) = v;
  }
}

// ---------------- RK4 SEIR: one thread per row ----------------------------
__global__ void rk4_traj(const float* __restrict__ bgs,
                         const float* __restrict__ xx,
                         float* __restrict__ out,
                         int rowOffset, int rows, int T) {
  const int r = blockIdx.x * blockDim.x + threadIdx.x;
  if (r >= rows) return;
  const size_t grow = (size_t)rowOffset + r;

  const float4 bg = *(const float4*)(bgs + (size_t)r * 4);
  const float beta = bg.x, gamma = bg.y, sigma = bg.z;

  const float4 iv = *(const float4*)(xx + grow * 80);
  float S = iv.x, E = iv.y, I = iv.z, R = iv.w;
  float* o = out + grow * (size_t)T * 4;
  *(float4*)o = iv;

#define DERIVS(S_, E_, I_, dS, dE, dI, dR)      \
  {                                             \
    float SI = beta * (S_) * (I_);              \
    float sE = sigma * (E_);                    \
    float gI = gamma * (I_);                    \
    dS = -SI; dE = SI - sE; dI = sE - gI; dR = gI; \
  }

  for (int t = 1; t < T; ++t) {
    float k1S, k1E, k1I, k1R; DERIVS(S, E, I, k1S, k1E, k1I, k1R);
    float k2S, k2E, k2I, k2R; DERIVS(S + 0.5f * k1S, E + 0.5f * k1E, I + 0.5f * k1I, k2S, k2E, k2I, k2R);
    float k3S, k3E, k3I, k3R; DERIVS(S + 0.5f * k2S, E + 0.5f * k2E, I + 0.5f * k2I, k3S, k3E, k3I, k3R);
    float k4S, k4E, k4I, k4R; DERIVS(S + k3S, E + k3E, I + k3I, k4S, k4E, k4I, k4R);
    S += (k1S + 2.f * k2S + 2.f * k3S + k4S) * (1.f / 6.f);
    E += (k1E + 2.f * k2E + 2.f * k3E + k4E) * (1.f / 6.f);
    I += (k1I + 2.f * k2I + 2.f * k3I + k4I) * (1.f / 6.f);
    R += (k1R + 2.f * k2R + 2.f * k3R + k4R) * (1.f / 6.f);
    *(float4*)(o + (size_t)t * 4) = make_float4(S, E, I, R);
  }
#undef DERIVS
}

// --------------------------------------------------------------------------
extern "C" void kernel_launch(void* const* d_in, const int* in_sizes, int n_in,
                              void* d_out, int out_size, void* d_ws, size_t ws_size,
                              hipStream_t stream) {
  const float* xx = (const float*)d_in[0];
  const float* W[7];
  const float* bb[7];
  for (int i = 0; i < 7; ++i) {
    W[i]  = (const float*)d_in[1 + 2 * i];
    bb[i] = (const float*)d_in[2 + 2 * i];
  }
  const int B = in_sizes[0] / 80;
  const int T = out_size / (B * 4);
  float* out = (float*)d_out;

  hipFuncSetAttribute((const void*)gemm8,
                      hipFuncAttributeMaxDynamicSharedMemorySize, 131072);

  uint8_t* ws = (uint8_t*)d_ws;
  size_t off = 0;
  auto alloc = [&](size_t bytes) -> uint8_t* {
    uint8_t* p = ws + off;
    off += (bytes + 255) & ~(size_t)255;
    return p;
  };

  unsigned short* WTl[6];
  WTl[0] = (unsigned short*)alloc((size_t)1024 * 128 * 2);
  for (int i = 1; i < 6; ++i) WTl[i] = (unsigned short*)alloc((size_t)1024 * 1024 * 2);

  // ws_size is LIMITED (R5-R7 aborts were workspace overflow) — chunk B.
  const size_t weightBytes = off;
  const size_t avail = ws_size > weightBytes ? ws_size - weightBytes : 0;
  int Bc = (int)(avail / 4368);  // per-row: 128*2 (X0) + 2*1024*2 (ping-pong) + 16 (bgs)
  Bc = (Bc / 256) * 256;
  if (Bc > B) Bc = B;
  if (Bc < 256) Bc = 256;

  unsigned short* X0   = (unsigned short*)alloc((size_t)Bc * 128 * 2);
  unsigned short* buf0 = (unsigned short*)alloc((size_t)Bc * 1024 * 2);
  unsigned short* buf1 = (unsigned short*)alloc((size_t)Bc * 1024 * 2);
  float* bgs           = (float*)alloc((size_t)Bc * 4 * 4);

  // one-time weight transposes (bf16)
  {
    dim3 blk(32, 8);
    transpose_cast<<<dim3(32, 4), blk, 0, stream>>>(W[0], WTl[0], 80, 1024, 128);
    for (int i = 1; i < 6; ++i)
      transpose_cast<<<dim3(32, 32), blk, 0, stream>>>(W[i], WTl[i], 1024, 1024, 1024);
  }

  for (int r0 = 0; r0 < B; r0 += Bc) {
    const int rows = (B - r0 < Bc) ? (B - r0) : Bc;

    {
      const int n = rows * 128;
      prep_x0<<<(n + 255) / 256, 256, 0, stream>>>(xx, X0, r0, rows);
    }

    // layer 0: K=128, m97-structure kernel
    gemm_mlp<<<dim3(8, rows / 128), 256, 0, stream>>>(X0, WTl[0], bb[0], buf0,
                                                      rows, 1024, 128, 1);

    // layers 1-5: 256^2 8-phase kernel
    const int nwg = (rows / 256) * 4;
    gemm8<<<nwg, 512, 131072, stream>>>(buf0, WTl[1], bb[1], buf1, rows, 1024, 1024);
    gemm8<<<nwg, 512, 131072, stream>>>(buf1, WTl[2], bb[2], buf0, rows, 1024, 1024);
    gemm8<<<nwg, 512, 131072, stream>>>(buf0, WTl[3], bb[3], buf1, rows, 1024, 1024);
    gemm8<<<nwg, 512, 131072, stream>>>(buf1, WTl[4], bb[4], buf0, rows, 1024, 1024);
    gemm8<<<nwg, 512, 131072, stream>>>(buf0, WTl[5], bb[5], buf1, rows, 1024, 1024);

    head_gemv<<<rows / 4, 256, 0, stream>>>(buf1, W[6], bb[6], bgs, rows);
    rk4_traj<<<(rows + 255) / 256, 256, 0, stream>>>(bgs, xx, out, r0, rows, T);
  }
}

// Round 9
// 959.863 us; speedup vs baseline: 1.1901x; 1.0538x over previous
//
#include <hip/hip_runtime.h>
#include <stdint.h>

typedef short s16x8 __attribute__((ext_vector_type(8)));
typedef __bf16 bf16x8 __attribute__((ext_vector_type(8)));
typedef float f32x4 __attribute__((ext_vector_type(4)));

typedef const __attribute__((address_space(1))) void* gas_ptr;
typedef __attribute__((address_space(3))) void* las_ptr;

__device__ __forceinline__ unsigned short f2bf(float f) {
  unsigned u = __builtin_bit_cast(unsigned, f);
  u += 0x7FFFu + ((u >> 16) & 1u);   // round-to-nearest-even
  return (unsigned short)(u >> 16);
}
__device__ __forceinline__ float bf2f(unsigned short h) {
  return __builtin_bit_cast(float, (unsigned)h << 16);
}
__device__ __forceinline__ void async16(const void* g, void* l) {
  __builtin_amdgcn_global_load_lds((gas_ptr)g, (las_ptr)l, 16, 0, 0);
}

// ---------------- prep: cast + pad X0 to [rows][128] bf16 ----------------
__global__ void prep_x0(const float* __restrict__ xx, unsigned short* __restrict__ X0,
                        int rowOffset, int rows) {
  int idx = blockIdx.x * blockDim.x + threadIdx.x;
  if (idx >= rows * 128) return;
  int r = idx >> 7, c = idx & 127;
  float v = (c < 80) ? xx[(size_t)(rowOffset + r) * 80 + c] : 0.f;
  X0[(size_t)r * 128 + c] = f2bf(v);
}

// ---------------- prep: all 6 weight transposes in ONE dispatch -----------
struct TP {
  const float* W[6];
  unsigned short* WT[6];
};

__global__ void transpose_all(TP tp) {
  const int z = blockIdx.z;
  const int K  = (z == 0) ? 80  : 1024;
  const int KP = (z == 0) ? 128 : 1024;
  if (blockIdx.y * 32 >= KP) return;
  __shared__ float tile[32][33];
  const int n0 = blockIdx.x * 32, k0 = blockIdx.y * 32;
  const int tx = threadIdx.x, ty = threadIdx.y;
  const float* W = tp.W[z];
  unsigned short* WT = tp.WT[z];
  #pragma unroll
  for (int j = 0; j < 32; j += 8) {
    int k = k0 + ty + j;
    tile[ty + j][tx] = (k < K) ? W[(size_t)k * 1024 + n0 + tx] : 0.f;
  }
  __syncthreads();
  #pragma unroll
  for (int j = 0; j < 32; j += 8) {
    WT[(size_t)(n0 + ty + j) * KP + k0 + tx] = f2bf(tile[tx][ty + j]);
  }
}

// ---------------- small GEMM (layer 0, K=128): m97 structure --------------
#define BM 128
#define BN 128
#define BK 64

__global__ void gemm_mlp(const unsigned short* __restrict__ A,
                         const unsigned short* __restrict__ BT,
                         const float* __restrict__ bias,
                         unsigned short* __restrict__ C,
                         int M, int N, int K, int leaky) {
  __shared__ unsigned short As[BM * BK];
  __shared__ unsigned short Bs[BN * BK];

  const int tid  = threadIdx.x;
  const int wid  = tid >> 6;
  const int lane = tid & 63;
  const int wr = (wid >> 1) * 64;
  const int wc = (wid & 1) * 64;
  const int bn = blockIdx.x * BN;
  const int bm = blockIdx.y * BM;

  const int srow = lane >> 3;
  const int scol = (lane & 7) * 8;

  f32x4 acc[4][4] = {};

  const unsigned short* aTile = A  + (size_t)bm * K;
  const unsigned short* bTile = BT + (size_t)bn * K;

  for (int k0 = 0; k0 < K; k0 += BK) {
    #pragma unroll
    for (int j = 0; j < 4; ++j) {
      const int rg = wid + j * 4;
      async16(aTile + (size_t)(rg * 8 + srow) * K + k0 + scol, &As[rg * 8 * BK]);
      async16(bTile + (size_t)(rg * 8 + srow) * K + k0 + scol, &Bs[rg * 8 * BK]);
    }
    __syncthreads();

    const int fr = lane & 15;
    const int kq = (lane >> 4) * 8;
    #pragma unroll
    for (int ks = 0; ks < BK; ks += 32) {
      const int kk = ks + kq;
      bf16x8 af[4], bv[4];
      #pragma unroll
      for (int m = 0; m < 4; ++m)
        af[m] = __builtin_bit_cast(bf16x8, *(const s16x8*)&As[(wr + m * 16 + fr) * BK + kk]);
      #pragma unroll
      for (int n = 0; n < 4; ++n)
        bv[n] = __builtin_bit_cast(bf16x8, *(const s16x8*)&Bs[(wc + n * 16 + fr) * BK + kk]);
      #pragma unroll
      for (int m = 0; m < 4; ++m)
        #pragma unroll
        for (int n = 0; n < 4; ++n)
          acc[m][n] = __builtin_amdgcn_mfma_f32_16x16x32_bf16(af[m], bv[n], acc[m][n], 0, 0, 0);
    }
    __syncthreads();
  }

  const int fcol = lane & 15;
  const int frow = (lane >> 4) * 4;
  #pragma unroll
  for (int m = 0; m < 4; ++m) {
    #pragma unroll
    for (int n = 0; n < 4; ++n) {
      const int col = bn + wc + n * 16 + fcol;
      const float bb = bias[col];
      #pragma unroll
      for (int r = 0; r < 4; ++r) {
        const int row = bm + wr + m * 16 + frow + r;
        float v = acc[m][n][r] + bb;
        if (leaky) v = (v > 0.f) ? v : 0.01f * v;
        C[(size_t)row * N + col] = f2bf(v);
      }
    }
  }
}

// ---------------- 256x256x64 8-phase GEMM (layers 1-5, K=1024) ------------
// Schedule = R3-benched variant. HEAD=0: LDS-staged vectorized C store.
// HEAD=1 (layer 5): no C store; epilogue computes leaky(acc+bias) dotted
// with W6 -> per-N-tile partials partial[nt][row][4] (summed by rk4).

__device__ __forceinline__ void stage_half(const char* srcRow0, size_t ldb,
                                           char* ldsHalf, int w, int rsub, int usw) {
  #pragma unroll
  for (int l = 0; l < 2; ++l) {
    const char* src = srcRow0 + (size_t)((l * 8 + w) * 8 + rsub) * ldb + usw;
    async16(src, ldsHalf + (l * 8 + w) * 1024);
  }
}

#define MFMA16 __builtin_amdgcn_mfma_f32_16x16x32_bf16
#define EPAD 72
#define EBYTES (64 * EPAD * 2)   // 9216 B per wave

template <int HEAD>
__global__ __launch_bounds__(512, 2)
void gemm8(const unsigned short* __restrict__ A,
           const unsigned short* __restrict__ BT,
           const float* __restrict__ bias,
           unsigned short* __restrict__ C,
           const float* __restrict__ W6,
           float* __restrict__ partial,
           int M, int N, int K) {
  extern __shared__ char smem[];
  char* smA = smem;             // [2][32768]
  char* smB = smem + 65536;     // [2][32768]
  const unsigned short* sA = (const unsigned short*)smA;
  const unsigned short* sB = (const unsigned short*)smB;
  const int NTk = K >> 6;

  const int tid  = threadIdx.x;
  const int w    = tid >> 6;
  const int lane = tid & 63;

  // bijective XCD-chunked block swizzle (m204)
  const int nwg = gridDim.x;
  const int bid = blockIdx.x;
  const int q = nwg >> 3, r = nwg & 7;
  const int xcd = bid & 7, idx = bid >> 3;
  const int wg = (xcd < r ? xcd * (q + 1) : r * (q + 1) + (xcd - r) * q) + idx;
  const int nNT = N >> 8;
  const int mtile = wg / nNT, ntile = wg % nNT;   // N fastest
  const int bm = mtile << 8, bn = ntile << 8;

  const int wr = (w >> 2) << 7;      // 0 / 128
  const int wc = (w & 3) << 6;       // 0/64/128/192
  const int fr = lane & 15;
  const int e0 = lane >> 4;
  const int sw = lane & 7;
  const int rsub = lane >> 3;
  const int usw  = ((sw ^ rsub) << 4);         // pre-swizzled global unit offset
  const int col0 = (((e0)     ^ sw) << 3);     // swizzled LDS element offset, ks=0
  const int col1 = (((e0 + 4) ^ sw) << 3);     // ks=32

  const size_t ldb = (size_t)K * 2;
  const char* Ab = (const char*)A  + (size_t)bm * ldb;
  const char* Bb = (const char*)BT + (size_t)bn * ldb;

  f32x4 acc[8][4] = {};

#define RDA(c_, row_, col_) __builtin_bit_cast(bf16x8, *(const s16x8*)&sA[(c_) * 16384 + (row_) * 64 + (col_)])
#define RDB(c_, row_, col_) __builtin_bit_cast(bf16x8, *(const s16x8*)&sB[(c_) * 16384 + (row_) * 64 + (col_)])

  // prologue: tile0 fully, tile1 B-halves (A(1) staged in kt=0 P0/P1)
  stage_half(Bb,                    ldb, smB,                  w, rsub, usw);  // SB0(0)
  stage_half(Bb + 128 * ldb,        ldb, smB + 16384,          w, rsub, usw);  // SB1(0)
  stage_half(Ab,                    ldb, smA,                  w, rsub, usw);  // SA0(0)
  stage_half(Ab + 128 * ldb,        ldb, smA + 16384,          w, rsub, usw);  // SA1(0)
  stage_half(Bb + 128,              ldb, smB + 32768,          w, rsub, usw);  // SB0(1)
  stage_half(Bb + 128 * ldb + 128,  ldb, smB + 32768 + 16384,  w, rsub, usw);  // SB1(1)
  asm volatile("s_waitcnt vmcnt(4)" ::: "memory");   // tile0 complete
  __builtin_amdgcn_s_barrier();

  for (int kt = 0; kt < NTk; ++kt) {
    const int c = kt & 1;
    bf16x8 aF[4][2], bF[4][2];

    // P0: A(m0-3)+B(n0-1) reads; stage SA0(kt+1); Q0
    #pragma unroll
    for (int m = 0; m < 4; ++m) {
      const int row = wr + m * 16 + fr;
      aF[m][0] = RDA(c, row, col0);
      aF[m][1] = RDA(c, row, col1);
    }
    #pragma unroll
    for (int n = 0; n < 2; ++n) {
      const int row = wc + n * 16 + fr;
      bF[n][0] = RDB(c, row, col0);
      bF[n][1] = RDB(c, row, col1);
    }
    if (kt + 1 < NTk)
      stage_half(Ab + (size_t)(kt + 1) * 128, ldb, smA + (c ^ 1) * 32768, w, rsub, usw);
    __builtin_amdgcn_s_barrier();
    __builtin_amdgcn_s_setprio(1);
    #pragma unroll
    for (int m = 0; m < 4; ++m)
      #pragma unroll
      for (int n = 0; n < 2; ++n) {
        acc[m][n] = MFMA16(aF[m][0], bF[n][0], acc[m][n], 0, 0, 0);
        acc[m][n] = MFMA16(aF[m][1], bF[n][1], acc[m][n], 0, 0, 0);
      }
    __builtin_amdgcn_s_setprio(0);
    __builtin_amdgcn_s_barrier();

    // P1: B(n2-3) reads; stage SA1(kt+1); Q1
    #pragma unroll
    for (int n = 2; n < 4; ++n) {
      const int row = wc + n * 16 + fr;
      bF[n][0] = RDB(c, row, col0);
      bF[n][1] = RDB(c, row, col1);
    }
    if (kt + 1 < NTk)
      stage_half(Ab + 128 * ldb + (size_t)(kt + 1) * 128, ldb,
                 smA + (c ^ 1) * 32768 + 16384, w, rsub, usw);
    __builtin_amdgcn_s_barrier();
    __builtin_amdgcn_s_setprio(1);
    #pragma unroll
    for (int m = 0; m < 4; ++m)
      #pragma unroll
      for (int n = 2; n < 4; ++n) {
        acc[m][n] = MFMA16(aF[m][0], bF[n][0], acc[m][n], 0, 0, 0);
        acc[m][n] = MFMA16(aF[m][1], bF[n][1], acc[m][n], 0, 0, 0);
      }
    __builtin_amdgcn_s_setprio(0);
    __builtin_amdgcn_s_barrier();

    // P2: A(m4-7) reads; stage SB0(kt+2); Q2
    #pragma unroll
    for (int m = 0; m < 4; ++m) {
      const int row = wr + (m + 4) * 16 + fr;
      aF[m][0] = RDA(c, row, col0);
      aF[m][1] = RDA(c, row, col1);
    }
    if (kt + 2 < NTk)
      stage_half(Bb + (size_t)(kt + 2) * 128, ldb, smB + c * 32768, w, rsub, usw);
    __builtin_amdgcn_s_barrier();
    __builtin_amdgcn_s_setprio(1);
    #pragma unroll
    for (int m = 0; m < 4; ++m)
      #pragma unroll
      for (int n = 0; n < 2; ++n) {
        acc[m + 4][n] = MFMA16(aF[m][0], bF[n][0], acc[m + 4][n], 0, 0, 0);
        acc[m + 4][n] = MFMA16(aF[m][1], bF[n][1], acc[m + 4][n], 0, 0, 0);
      }
    __builtin_amdgcn_s_setprio(0);
    __builtin_amdgcn_s_barrier();

    // P3: stage SB1(kt+2); Q3; counted vmcnt
    if (kt + 2 < NTk)
      stage_half(Bb + 128 * ldb + (size_t)(kt + 2) * 128, ldb,
                 smB + c * 32768 + 16384, w, rsub, usw);
    __builtin_amdgcn_s_barrier();
    __builtin_amdgcn_s_setprio(1);
    #pragma unroll
    for (int m = 0; m < 4; ++m)
      #pragma unroll
      for (int n = 2; n < 4; ++n) {
        acc[m + 4][n] = MFMA16(aF[m][0], bF[n][0], acc[m + 4][n], 0, 0, 0);
        acc[m + 4][n] = MFMA16(aF[m][1], bF[n][1], acc[m + 4][n], 0, 0, 0);
      }
    __builtin_amdgcn_s_setprio(0);
    if (kt + 2 < NTk) asm volatile("s_waitcnt vmcnt(4)" ::: "memory");
    else              asm volatile("s_waitcnt vmcnt(0)" ::: "memory");
    __builtin_amdgcn_s_barrier();
  }

#undef RDA
#undef RDB

  const int fcol = lane & 15;
  float bbv[4];
  #pragma unroll
  for (int n = 0; n < 4; ++n) bbv[n] = bias[bn + wc + n * 16 + fcol];

  if constexpr (HEAD) {
    // head epilogue: dot leaky(acc+bias) with W6 cols; reduce over fcol group
    float w6c[4][3];
    #pragma unroll
    for (int n = 0; n < 4; ++n) {
      const int col = bn + wc + n * 16 + fcol;
      #pragma unroll
      for (int j = 0; j < 3; ++j) w6c[n][j] = W6[col * 3 + j];
    }
    const int nt = bn >> 8;
    #pragma unroll
    for (int mh = 0; mh < 2; ++mh)
      #pragma unroll
      for (int mm = 0; mm < 4; ++mm)
        #pragma unroll
        for (int rr = 0; rr < 4; ++rr) {
          float s0 = 0.f, s1 = 0.f, s2 = 0.f;
          #pragma unroll
          for (int n = 0; n < 4; ++n) {
            float v = acc[mh * 4 + mm][n][rr] + bbv[n];
            v = (v > 0.f) ? v : 0.01f * v;
            s0 = fmaf(v, w6c[n][0], s0);
            s1 = fmaf(v, w6c[n][1], s1);
            s2 = fmaf(v, w6c[n][2], s2);
          }
          #pragma unroll
          for (int off = 1; off < 16; off <<= 1) {
            s0 += __shfl_xor(s0, off);
            s1 += __shfl_xor(s1, off);
            s2 += __shfl_xor(s2, off);
          }
          if (fcol == 0) {
            const int row = bm + wr + mh * 64 + mm * 16 + e0 * 4 + rr;
            *(float4*)&partial[((size_t)nt * M + row) * 4] =
                make_float4(s0, s1, s2, 0.f);
          }
        }
  } else {
    // epilogue: per-wave LDS transpose -> vectorized bf16 stores (128B segs)
    unsigned short* eb = (unsigned short*)(smem + w * EBYTES);  // [64][EPAD]
    const int r8 = lane >> 3, c8 = (lane & 7) * 8;
    #pragma unroll
    for (int mh = 0; mh < 2; ++mh) {
      #pragma unroll
      for (int mm = 0; mm < 4; ++mm)
        #pragma unroll
        for (int n = 0; n < 4; ++n)
          #pragma unroll
          for (int rr = 0; rr < 4; ++rr) {
            const int row64 = mm * 16 + e0 * 4 + rr;
            float v = acc[mh * 4 + mm][n][rr] + bbv[n];
            v = (v > 0.f) ? v : 0.01f * v;
            eb[row64 * EPAD + n * 16 + fcol] = f2bf(v);
          }
      asm volatile("" ::: "memory");
      #pragma unroll
      for (int rg = 0; rg < 8; ++rg) {
        const int row64 = rg * 8 + r8;
        s16x8 vv = *(const s16x8*)&eb[row64 * EPAD + c8];
        const int rl = bm + wr + mh * 64 + row64;
        *(s16x8*)&C[(size_t)rl * N + bn + wc + c8] = vv;
      }
      asm volatile("" ::: "memory");
    }
  }
}

// ---------------- RK4 SEIR: one thread per row ----------------------------
__global__ void rk4_traj(const float* __restrict__ partial,  // [4][rows][4]
                         const float* __restrict__ b6,
                         const float* __restrict__ xx,
                         float* __restrict__ out,
                         int rowOffset, int rows, int T) {
  const int r = blockIdx.x * blockDim.x + threadIdx.x;
  if (r >= rows) return;
  const size_t grow = (size_t)rowOffset + r;

  float4 p0 = *(const float4*)&partial[((size_t)0 * rows + r) * 4];
  float4 p1 = *(const float4*)&partial[((size_t)1 * rows + r) * 4];
  float4 p2 = *(const float4*)&partial[((size_t)2 * rows + r) * 4];
  float4 p3 = *(const float4*)&partial[((size_t)3 * rows + r) * 4];
  const float beta  = p0.x + p1.x + p2.x + p3.x + b6[0];
  const float gamma = p0.y + p1.y + p2.y + p3.y + b6[1];
  const float sigma = p0.z + p1.z + p2.z + p3.z + b6[2];

  const float4 iv = *(const float4*)(xx + grow * 80);
  float S = iv.x, E = iv.y, I = iv.z, R = iv.w;
  float* o = out + grow * (size_t)T * 4;
  *(float4*)o = iv;

#define DERIVS(S_, E_, I_, dS, dE, dI, dR)      \
  {                                             \
    float SI = beta * (S_) * (I_);              \
    float sE = sigma * (E_);                    \
    float gI = gamma * (I_);                    \
    dS = -SI; dE = SI - sE; dI = sE - gI; dR = gI; \
  }

  for (int t = 1; t < T; ++t) {
    float k1S, k1E, k1I, k1R; DERIVS(S, E, I, k1S, k1E, k1I, k1R);
    float k2S, k2E, k2I, k2R; DERIVS(S + 0.5f * k1S, E + 0.5f * k1E, I + 0.5f * k1I, k2S, k2E, k2I, k2R);
    float k3S, k3E, k3I, k3R; DERIVS(S + 0.5f * k2S, E + 0.5f * k2E, I + 0.5f * k2I, k3S, k3E, k3I, k3R);
    float k4S, k4E, k4I, k4R; DERIVS(S + k3S, E + k3E, I + k3I, k4S, k4E, k4I, k4R);
    S += (k1S + 2.f * k2S + 2.f * k3S + k4S) * (1.f / 6.f);
    E += (k1E + 2.f * k2E + 2.f * k3E + k4E) * (1.f / 6.f);
    I += (k1I + 2.f * k2I + 2.f * k3I + k4I) * (1.f / 6.f);
    R += (k1R + 2.f * k2R + 2.f * k3R + k4R) * (1.f / 6.f);
    *(float4*)(o + (size_t)t * 4) = make_float4(S, E, I, R);
  }
#undef DERIVS
}

// --------------------------------------------------------------------------
extern "C" void kernel_launch(void* const* d_in, const int* in_sizes, int n_in,
                              void* d_out, int out_size, void* d_ws, size_t ws_size,
                              hipStream_t stream) {
  const float* xx = (const float*)d_in[0];
  const float* W[7];
  const float* bb[7];
  for (int i = 0; i < 7; ++i) {
    W[i]  = (const float*)d_in[1 + 2 * i];
    bb[i] = (const float*)d_in[2 + 2 * i];
  }
  const int B = in_sizes[0] / 80;
  const int T = out_size / (B * 4);
  float* out = (float*)d_out;

  {
    auto k0 = gemm8<0>;
    auto k1 = gemm8<1>;
    hipFuncSetAttribute((const void*)k0, hipFuncAttributeMaxDynamicSharedMemorySize, 131072);
    hipFuncSetAttribute((const void*)k1, hipFuncAttributeMaxDynamicSharedMemorySize, 131072);
  }

  uint8_t* ws = (uint8_t*)d_ws;
  size_t off = 0;
  auto alloc = [&](size_t bytes) -> uint8_t* {
    uint8_t* p = ws + off;
    off += (bytes + 255) & ~(size_t)255;
    return p;
  };

  unsigned short* WTl[6];
  WTl[0] = (unsigned short*)alloc((size_t)1024 * 128 * 2);
  for (int i = 1; i < 6; ++i) WTl[i] = (unsigned short*)alloc((size_t)1024 * 1024 * 2);

  const size_t weightBytes = off;
  const size_t avail = ws_size > weightBytes ? ws_size - weightBytes : 0;
  // per-row: 256 (X0) + 2048 (buf0) + 2048 (buf1) + 64 (partial) = 4416 B
  int Bc = (int)(avail / 4416);
  Bc = (Bc / 256) * 256;
  if (Bc > B) Bc = B;
  if (Bc < 256) Bc = 256;

  unsigned short* X0   = (unsigned short*)alloc((size_t)Bc * 128 * 2);
  unsigned short* buf0 = (unsigned short*)alloc((size_t)Bc * 1024 * 2);
  unsigned short* buf1 = (unsigned short*)alloc((size_t)Bc * 1024 * 2);
  float* partial       = (float*)alloc((size_t)Bc * 4 * 16);

  // one-time weight transposes (bf16), single dispatch
  {
    TP tp;
    for (int i = 0; i < 6; ++i) { tp.W[i] = W[i]; tp.WT[i] = WTl[i]; }
    transpose_all<<<dim3(32, 32, 6), dim3(32, 8), 0, stream>>>(tp);
  }

  for (int r0 = 0; r0 < B; r0 += Bc) {
    const int rows = (B - r0 < Bc) ? (B - r0) : Bc;

    {
      const int n = rows * 128;
      prep_x0<<<(n + 255) / 256, 256, 0, stream>>>(xx, X0, r0, rows);
    }

    // layer 0: K=128, m97-structure kernel
    gemm_mlp<<<dim3(8, rows / 128), 256, 0, stream>>>(X0, WTl[0], bb[0], buf0,
                                                      rows, 1024, 128, 1);

    // layers 1-4: 256^2 8-phase kernel
    const int nwg = (rows / 256) * 4;
    gemm8<0><<<nwg, 512, 131072, stream>>>(buf0, WTl[1], bb[1], buf1, nullptr, nullptr, rows, 1024, 1024);
    gemm8<0><<<nwg, 512, 131072, stream>>>(buf1, WTl[2], bb[2], buf0, nullptr, nullptr, rows, 1024, 1024);
    gemm8<0><<<nwg, 512, 131072, stream>>>(buf0, WTl[3], bb[3], buf1, nullptr, nullptr, rows, 1024, 1024);
    gemm8<0><<<nwg, 512, 131072, stream>>>(buf1, WTl[4], bb[4], buf0, nullptr, nullptr, rows, 1024, 1024);

    // layer 5 + head fused: no C write, emits partial[4][rows][4]
    gemm8<1><<<nwg, 512, 131072, stream>>>(buf0, WTl[5], bb[5], nullptr, W[6], partial, rows, 1024, 1024);

    rk4_traj<<<(rows + 255) / 256, 256, 0, stream>>>(partial, bb[6], xx, out, r0, rows, T);
  }
}